// Round 2
// baseline (11216.402 us; speedup 1.0000x reference)
//
#include <hip/hip_runtime.h>
#include <math.h>

// Problem constants
#define SS 256   // encoder seq len
#define BB 256   // batch
#define HH 512   // hidden
#define OO 64    // output dim
#define NSTEP 63 // only outs[:63] are used

// ---------------------------------------------------------------------------
// K0: EW[m, h] = sum_k enc[m, k] * Wa_bot[k, h]   (M=65536, K=512, N=512)
// 128x128 tile, BK=8, 256 threads, 8x8 per thread, fp32.
// ---------------------------------------------------------------------------
__global__ __launch_bounds__(256) void k_ew_gemm(const float* __restrict__ A,
                                                 const float* __restrict__ Bm,
                                                 float* __restrict__ C)
{
    __shared__ float As[8][132];
    __shared__ float Bs[8][132];
    const int tid = threadIdx.x;
    const int bm = blockIdx.x * 128;
    const int bn = blockIdx.y * 128;
    const int tx = tid & 15;
    const int ty = tid >> 4;
    const int a_row = tid >> 1;
    const int a_k4 = (tid & 1) * 4;
    const int b_row = tid >> 5;
    const int b_n4 = (tid & 31) * 4;

    float acc[8][8];
#pragma unroll
    for (int i = 0; i < 8; i++)
#pragma unroll
        for (int j = 0; j < 8; j++) acc[i][j] = 0.f;

    for (int kt = 0; kt < 512; kt += 8) {
        float4 av = *(const float4*)(A + (size_t)(bm + a_row) * 512 + kt + a_k4);
        As[a_k4 + 0][a_row] = av.x;
        As[a_k4 + 1][a_row] = av.y;
        As[a_k4 + 2][a_row] = av.z;
        As[a_k4 + 3][a_row] = av.w;
        *(float4*)(&Bs[b_row][b_n4]) = *(const float4*)(Bm + (size_t)(kt + b_row) * 512 + bn + b_n4);
        __syncthreads();
#pragma unroll
        for (int kk = 0; kk < 8; kk++) {
            float av8[8], bv8[8];
            *(float4*)&av8[0] = *(const float4*)&As[kk][ty * 4];
            *(float4*)&av8[4] = *(const float4*)&As[kk][64 + ty * 4];
            *(float4*)&bv8[0] = *(const float4*)&Bs[kk][tx * 4];
            *(float4*)&bv8[4] = *(const float4*)&Bs[kk][64 + tx * 4];
#pragma unroll
            for (int i = 0; i < 8; i++)
#pragma unroll
                for (int j = 0; j < 8; j++) acc[i][j] += av8[i] * bv8[j];
        }
        __syncthreads();
    }
#pragma unroll
    for (int i = 0; i < 8; i++) {
        int m = bm + ((i < 4) ? (ty * 4 + i) : (64 + ty * 4 + i - 4));
        float4 o0 = make_float4(acc[i][0], acc[i][1], acc[i][2], acc[i][3]);
        float4 o1 = make_float4(acc[i][4], acc[i][5], acc[i][6], acc[i][7]);
        *(float4*)(C + (size_t)m * 512 + bn + tx * 4) = o0;
        *(float4*)(C + (size_t)m * 512 + bn + 64 + tx * 4) = o1;
    }
}

// ---------------------------------------------------------------------------
// Step GEMM (32x32 tile, BK=32, 256 threads, 2x2/thread, M=256).
// Reads weights DIRECTLY from input tensors (no staging buffers in ws):
// mode 0 (q init):  C = A2 @ Wa_top + ba                 -> C0[m*512+n]
// mode 1 (h_new):   C = tanh([A0|A1|A2] @ [W_ih|W_hh]^T + b_ih + b_hh)
//                   B_eff[k][n] = k<576 ? W_ih[n*576+k] : W_hh[n*512+k-576]
// mode 2 (out+q):   n<64:  C = A2 @ Wo^T + bo -> ob, dout (b,o,t layout)
//                   n>=64: C = A2 @ Wa_top + ba -> qout
// ---------------------------------------------------------------------------
__device__ __forceinline__ float loadA_seg(const float* __restrict__ A0,
                                           const float* __restrict__ A1,
                                           const float* __restrict__ A2,
                                           int k1, int k2, int Ksz, int m, int k)
{
    if (k < k1) return A0[m * k1 + k];
    if (k < k2) return A1[m * (k2 - k1) + (k - k1)];
    return A2[(size_t)m * (Ksz - k2) + (k - k2)];
}

__global__ __launch_bounds__(256) void k_gemm32(
    int mode, int Ksz,
    const float* __restrict__ A0, const float* __restrict__ A1, const float* __restrict__ A2,
    int k1, int k2,
    const float* __restrict__ B0, const float* __restrict__ B1,
    const float* __restrict__ bias0, const float* __restrict__ bias1,
    float* __restrict__ C0,
    float* __restrict__ dout, int t,
    float* __restrict__ qout)
{
    __shared__ float As[32][33];
    __shared__ float Bs[32][33];
    const int tid = threadIdx.x;
    const int bn = blockIdx.x * 32;
    const int bm = blockIdx.y * 32;
    const int tx = tid & 15;
    const int ty = tid >> 4;
    const int l_row = tid >> 3;          // 0..31
    const int l_c4 = (tid & 7) * 4;      // 0,4,...,28

    float acc00 = 0.f, acc01 = 0.f, acc10 = 0.f, acc11 = 0.f;

    for (int kt = 0; kt < Ksz; kt += 32) {
        const int m = bm + l_row;
#pragma unroll
        for (int i = 0; i < 4; i++)
            As[l_c4 + i][l_row] = loadA_seg(A0, A1, A2, k1, k2, Ksz, m, kt + l_c4 + i);

        if (mode == 0) {
            // B0 = Wa_top, [k][n]
#pragma unroll
            for (int i = 0; i < 4; i++)
                Bs[l_row][l_c4 + i] = B0[(size_t)(kt + l_row) * 512 + bn + l_c4 + i];
        } else if (mode == 1) {
            // [n][k] transposed load; 576 is 32-aligned so tile never straddles
            if (kt < 576) {
#pragma unroll
                for (int i = 0; i < 4; i++)
                    Bs[l_c4 + i][l_row] = B0[(size_t)(bn + l_row) * 576 + kt + l_c4 + i];
            } else {
#pragma unroll
                for (int i = 0; i < 4; i++)
                    Bs[l_c4 + i][l_row] = B1[(size_t)(bn + l_row) * 512 + (kt - 576) + l_c4 + i];
            }
        } else {
            if (bn < 64) {
                // Wo [n][k] transposed load
#pragma unroll
                for (int i = 0; i < 4; i++)
                    Bs[l_c4 + i][l_row] = B0[(size_t)(bn + l_row) * 512 + kt + l_c4 + i];
            } else {
                // Wa_top [k][n]
#pragma unroll
                for (int i = 0; i < 4; i++)
                    Bs[l_row][l_c4 + i] = B1[(size_t)(kt + l_row) * 512 + (bn - 64) + l_c4 + i];
            }
        }
        __syncthreads();
#pragma unroll
        for (int kk = 0; kk < 32; kk++) {
            float a0 = As[kk][ty * 2 + 0];
            float a1 = As[kk][ty * 2 + 1];
            float b0 = Bs[kk][tx * 2 + 0];
            float b1 = Bs[kk][tx * 2 + 1];
            acc00 += a0 * b0; acc01 += a0 * b1;
            acc10 += a1 * b0; acc11 += a1 * b1;
        }
        __syncthreads();
    }

    float accs[2][2] = {{acc00, acc01}, {acc10, acc11}};
#pragma unroll
    for (int i = 0; i < 2; i++) {
#pragma unroll
        for (int j = 0; j < 2; j++) {
            const int m = bm + ty * 2 + i;
            const int n = bn + tx * 2 + j;
            float vv = accs[i][j];
            if (mode == 0) {
                vv += bias0[n];
                C0[(size_t)m * 512 + n] = vv;
            } else if (mode == 1) {
                vv += bias0[n] + bias1[n];
                C0[(size_t)m * 512 + n] = tanhf(vv);
            } else {
                if (n < 64) {
                    vv += bias0[n];
                    C0[m * 64 + n] = vv;
                    dout[(size_t)m * (OO * NSTEP) + n * NSTEP + t] = vv;
                } else {
                    vv += bias1[n - 64];
                    qout[m * 512 + (n - 64)] = vv;
                }
            }
        }
    }
}

// ---------------------------------------------------------------------------
// K2: fused scores + softmax + context for one batch element b (block = b).
// score[s] = sum_h v[h]*tanh(EW[s,b,h] + q[b,h]); attn = softmax_s;
// ctx[b,h] = sum_s attn[s]*enc[s,b,h].  512 threads (8 waves).
// ---------------------------------------------------------------------------
__global__ __launch_bounds__(512) void k_attn(const float* __restrict__ EW,
                                              const float* __restrict__ enc,
                                              const float* __restrict__ q,
                                              const float* __restrict__ vvec,
                                              float* __restrict__ ctx)
{
    __shared__ float qs[512];
    __shared__ float vs[512];
    __shared__ float sc[256];
    __shared__ float red[16];
    const int b = blockIdx.x;
    const int tid = threadIdx.x;
    qs[tid] = q[b * 512 + tid];
    vs[tid] = vvec[tid];
    __syncthreads();

    const int w = tid >> 6;
    const int l = tid & 63;
    const float* qp0 = qs + l * 4;
    const float* vp0 = vs + l * 4;
    const float* qp1 = qs + 256 + l * 4;
    const float* vp1 = vs + 256 + l * 4;

    for (int i = 0; i < 32; i++) {
        int s = w * 32 + i;
        const float4* p4 = (const float4*)(EW + ((size_t)(s * 256 + b)) * 512);
        float4 e0 = p4[l];
        float4 e1 = p4[l + 64];
        float a;
        a  = vp0[0] * tanhf(e0.x + qp0[0]);
        a += vp0[1] * tanhf(e0.y + qp0[1]);
        a += vp0[2] * tanhf(e0.z + qp0[2]);
        a += vp0[3] * tanhf(e0.w + qp0[3]);
        a += vp1[0] * tanhf(e1.x + qp1[0]);
        a += vp1[1] * tanhf(e1.y + qp1[1]);
        a += vp1[2] * tanhf(e1.z + qp1[2]);
        a += vp1[3] * tanhf(e1.w + qp1[3]);
#pragma unroll
        for (int off = 32; off; off >>= 1) a += __shfl_down(a, off);
        if (l == 0) sc[s] = a;
    }
    __syncthreads();

    // softmax (unnormalized exp in sc; fold 1/sum into context)
    if (tid < 256) {
        float m = sc[tid];
#pragma unroll
        for (int off = 32; off; off >>= 1) m = fmaxf(m, __shfl_down(m, off));
        if ((tid & 63) == 0) red[tid >> 6] = m;
    }
    __syncthreads();
    if (tid < 256) {
        float mx = fmaxf(fmaxf(red[0], red[1]), fmaxf(red[2], red[3]));
        float e = expf(sc[tid] - mx);
        sc[tid] = e;
        float ssum = e;
#pragma unroll
        for (int off = 32; off; off >>= 1) ssum += __shfl_down(ssum, off);
        if ((tid & 63) == 0) red[8 + (tid >> 6)] = ssum;
    }
    __syncthreads();
    const float inv = 1.0f / (red[8] + red[9] + red[10] + red[11]);

    // context: one h per thread
    const int h = tid;
    const float* ep = enc + b * 512 + h;
    float acc = 0.f;
#pragma unroll 4
    for (int s = 0; s < 256; s++) {
        acc += sc[s] * ep[(size_t)s * (256 * 512)];
    }
    ctx[b * 512 + h] = acc * inv;
}

// ---------------------------------------------------------------------------
// K4: per-b argmax over out_buf[b, 0..63] -> one-hot x[b, :]
// first-index tie-break to match jnp.argmax.
// ---------------------------------------------------------------------------
__global__ __launch_bounds__(256) void k_argmax(const float* __restrict__ out_buf,
                                                float* __restrict__ x)
{
    const int b = blockIdx.x * 4 + (threadIdx.x >> 6);
    const int l = threadIdx.x & 63;
    float v = out_buf[b * 64 + l];
    int bi = l;
#pragma unroll
    for (int off = 1; off < 64; off <<= 1) {
        float ov = __shfl_xor(v, off);
        int oi = __shfl_xor(bi, off);
        if (ov > v || (ov == v && oi < bi)) { v = ov; bi = oi; }
    }
    x[b * 64 + l] = (l == bi) ? 1.0f : 0.0f;
}

// ---------------------------------------------------------------------------
extern "C" void kernel_launch(void* const* d_in, const int* in_sizes, int n_in,
                              void* d_out, int out_size, void* d_ws, size_t ws_size,
                              hipStream_t stream)
{
    const float* sos  = (const float*)d_in[0];
    const float* h0   = (const float*)d_in[1];
    const float* enc  = (const float*)d_in[2];
    const float* Wa   = (const float*)d_in[3];
    const float* ba   = (const float*)d_in[4];
    const float* vvec = (const float*)d_in[5];
    const float* W_ih = (const float*)d_in[6];
    const float* b_ih = (const float*)d_in[7];
    const float* W_hh = (const float*)d_in[8];
    const float* b_hh = (const float*)d_in[9];
    const float* Wo   = (const float*)d_in[10];
    const float* bo   = (const float*)d_in[11];
    float* out = (float*)d_out;

    // Workspace: 34,111,488 floats = 136.4 MB (must stay under ws_size;
    // R0 failed because staging buffers pushed this past the budget and
    // silently corrupted adjacent allocations).
    float* ws = (float*)d_ws;
    float* EW  = ws; ws += (size_t)SS * BB * HH;   // 33,554,432
    float* q   = ws; ws += BB * HH;
    float* ctx = ws; ws += BB * HH;
    float* hb0 = ws; ws += BB * HH;
    float* hb1 = ws; ws += BB * HH;
    float* xb  = ws; ws += BB * OO;
    float* ob  = ws; ws += BB * OO;

    // ---- Precompute (once per call) ----
    // EW = enc @ Wa[H:]   (65536 x 512 x 512)
    k_ew_gemm<<<dim3(512, 4), 256, 0, stream>>>(enc, Wa + 512 * 512, EW);
    // initial q = h0 @ Wa[:H] + ba
    k_gemm32<<<dim3(16, 8), 256, 0, stream>>>(0, 512,
        nullptr, nullptr, h0, 0, 0, Wa, nullptr, ba, nullptr, q, nullptr, 0, nullptr);

    // ---- 63 decode steps ----
    for (int t = 0; t < NSTEP; t++) {
        const float* hin  = (t == 0) ? h0 : ((t & 1) ? hb0 : hb1);
        float*       hout = (t & 1) ? hb1 : hb0;
        const float* xin  = (t == 0) ? sos : xb;

        // attention: scores + softmax + context
        k_attn<<<256, 512, 0, stream>>>(EW, enc, q, vvec, ctx);

        // h_new = tanh([x, ctx] @ W_ih^T + h @ W_hh^T + b_ih + b_hh)
        k_gemm32<<<dim3(16, 8), 256, 0, stream>>>(1, 1088,
            xin, ctx, hin, 64, 576, W_ih, W_hh, b_ih, b_hh, hout, nullptr, 0, nullptr);

        // out = h_new @ Wo^T + bo (n<64) ; q_next = h_new @ Wa_top + ba (n>=64)
        k_gemm32<<<dim3(18, 8), 256, 0, stream>>>(2, 512,
            nullptr, nullptr, hout, 0, 0, Wo, Wa, bo, ba, ob, out, t, q);

        // x_next = one_hot(argmax(out))
        k_argmax<<<64, 256, 0, stream>>>(ob, xb);
    }
}

// Round 3
// 8742.214 us; speedup vs baseline: 1.2830x; 1.2830x over previous
//
#include <hip/hip_runtime.h>
#include <math.h>

// Problem constants
#define SS 256   // encoder seq len
#define BB 256   // batch
#define HH 512   // hidden
#define OO 64    // output dim
#define NSTEP 63 // only outs[:63] are used

// ---------------------------------------------------------------------------
// K0: EW = enc @ Wa_bot  (M=65536, K=512, N=512), fp32, 128x128 tile.
// Output relayout: row m = s*256+b  ->  EW[b][s][h]  (contiguous per batch b)
// ---------------------------------------------------------------------------
__global__ __launch_bounds__(256) void k_ew_gemm(const float* __restrict__ A,
                                                 const float* __restrict__ Bm,
                                                 float* __restrict__ C)
{
    __shared__ float As[8][132];
    __shared__ float Bs[8][132];
    const int tid = threadIdx.x;
    const int bm = blockIdx.x * 128;
    const int bn = blockIdx.y * 128;
    const int tx = tid & 15;
    const int ty = tid >> 4;
    const int a_row = tid >> 1;
    const int a_k4 = (tid & 1) * 4;
    const int b_row = tid >> 5;
    const int b_n4 = (tid & 31) * 4;

    float acc[8][8];
#pragma unroll
    for (int i = 0; i < 8; i++)
#pragma unroll
        for (int j = 0; j < 8; j++) acc[i][j] = 0.f;

    for (int kt = 0; kt < 512; kt += 8) {
        float4 av = *(const float4*)(A + (size_t)(bm + a_row) * 512 + kt + a_k4);
        As[a_k4 + 0][a_row] = av.x;
        As[a_k4 + 1][a_row] = av.y;
        As[a_k4 + 2][a_row] = av.z;
        As[a_k4 + 3][a_row] = av.w;
        *(float4*)(&Bs[b_row][b_n4]) = *(const float4*)(Bm + (size_t)(kt + b_row) * 512 + bn + b_n4);
        __syncthreads();
#pragma unroll
        for (int kk = 0; kk < 8; kk++) {
            float av8[8], bv8[8];
            *(float4*)&av8[0] = *(const float4*)&As[kk][ty * 4];
            *(float4*)&av8[4] = *(const float4*)&As[kk][64 + ty * 4];
            *(float4*)&bv8[0] = *(const float4*)&Bs[kk][tx * 4];
            *(float4*)&bv8[4] = *(const float4*)&Bs[kk][64 + tx * 4];
#pragma unroll
            for (int i = 0; i < 8; i++)
#pragma unroll
                for (int j = 0; j < 8; j++) acc[i][j] += av8[i] * bv8[j];
        }
        __syncthreads();
    }
#pragma unroll
    for (int i = 0; i < 8; i++) {
        int m = bm + ((i < 4) ? (ty * 4 + i) : (64 + ty * 4 + i - 4));
        int mrow = (m & 255) * 256 + (m >> 8);   // [b][s] relayout
        float4 o0 = make_float4(acc[i][0], acc[i][1], acc[i][2], acc[i][3]);
        float4 o1 = make_float4(acc[i][4], acc[i][5], acc[i][6], acc[i][7]);
        *(float4*)(C + (size_t)mrow * 512 + bn + tx * 4) = o0;
        *(float4*)(C + (size_t)mrow * 512 + bn + 64 + tx * 4) = o1;
    }
}

// ---------------------------------------------------------------------------
// q init: qpre = h0 @ Wa_top   (no bias; ba deferred to k_attn)
// 32x32 tile, BK=32, 256 thr, 2x2/thread.
// ---------------------------------------------------------------------------
__global__ __launch_bounds__(256) void k_qinit(const float* __restrict__ A,
                                               const float* __restrict__ Wa,
                                               float* __restrict__ qpre)
{
    __shared__ float As[32][33];
    __shared__ float Bs[32][33];
    const int tid = threadIdx.x;
    const int bn = blockIdx.x * 32;
    const int bm = blockIdx.y * 32;
    const int tx = tid & 15;
    const int ty = tid >> 4;
    const int l_row = tid >> 3;
    const int l_c4 = (tid & 7) * 4;

    float acc00 = 0.f, acc01 = 0.f, acc10 = 0.f, acc11 = 0.f;
    for (int kt = 0; kt < 512; kt += 32) {
#pragma unroll
        for (int i = 0; i < 4; i++)
            As[l_c4 + i][l_row] = A[(size_t)(bm + l_row) * 512 + kt + l_c4 + i];
#pragma unroll
        for (int i = 0; i < 4; i++)
            Bs[l_row][l_c4 + i] = Wa[(size_t)(kt + l_row) * 512 + bn + l_c4 + i];
        __syncthreads();
#pragma unroll
        for (int kk = 0; kk < 32; kk++) {
            float a0 = As[kk][ty * 2], a1 = As[kk][ty * 2 + 1];
            float b0 = Bs[kk][tx * 2], b1 = Bs[kk][tx * 2 + 1];
            acc00 += a0 * b0; acc01 += a0 * b1;
            acc10 += a1 * b0; acc11 += a1 * b1;
        }
        __syncthreads();
    }
    qpre[(size_t)(bm + ty * 2) * 512 + bn + tx * 2]     = acc00;
    qpre[(size_t)(bm + ty * 2) * 512 + bn + tx * 2 + 1] = acc01;
    qpre[(size_t)(bm + ty * 2 + 1) * 512 + bn + tx * 2]     = acc10;
    qpre[(size_t)(bm + ty * 2 + 1) * 512 + bn + tx * 2 + 1] = acc11;
}

// ---------------------------------------------------------------------------
// k_attn: per batch b: scores (tanh(EW[b][s]+q[b])·v), softmax_s, context.
// Also zeroes hpre_out (131072 f) and ob (16384 f) for this step's atomics.
// EW layout [b][s][h] (contiguous streaming per block). 512 threads.
// ---------------------------------------------------------------------------
__global__ __launch_bounds__(512) void k_attn(const float* __restrict__ EW,
                                              const float* __restrict__ enc,
                                              const float* __restrict__ qpre,
                                              const float* __restrict__ ba,
                                              const float* __restrict__ vvec,
                                              float* __restrict__ ctx,
                                              float* __restrict__ hpre_out,
                                              float* __restrict__ ob)
{
    __shared__ float qs[512];
    __shared__ float vs[512];
    __shared__ float sc[256];
    __shared__ float red[16];
    const int b = blockIdx.x;
    const int tid = threadIdx.x;

    // zero this step's atomic accumulators (576 floats per block)
    {
        int j = b * 576 + tid;
        // tid 0..511
        if (j < 131072 + b * 576 - b * 576) {} // no-op, keep simple below
    }
    {
        int base = b * 576;
        for (int j = tid; j < 576; j += 512) {
            int idx = base + j;
            if (idx < 131072) hpre_out[idx] = 0.f;
            else              ob[idx - 131072] = 0.f;
        }
    }

    qs[tid] = qpre[b * 512 + tid] + ba[tid];
    vs[tid] = vvec[tid];
    __syncthreads();

    const int w = tid >> 6;
    const int l = tid & 63;
    const float* qp0 = qs + l * 4;
    const float* vp0 = vs + l * 4;
    const float* qp1 = qs + 256 + l * 4;
    const float* vp1 = vs + 256 + l * 4;

    for (int i = 0; i < 32; i++) {
        int s = w * 32 + i;
        const float4* p4 = (const float4*)(EW + ((size_t)(b * 256 + s)) * 512);
        float4 e0 = p4[l];
        float4 e1 = p4[l + 64];
        float a;
        a  = vp0[0] * tanhf(e0.x + qp0[0]);
        a += vp0[1] * tanhf(e0.y + qp0[1]);
        a += vp0[2] * tanhf(e0.z + qp0[2]);
        a += vp0[3] * tanhf(e0.w + qp0[3]);
        a += vp1[0] * tanhf(e1.x + qp1[0]);
        a += vp1[1] * tanhf(e1.y + qp1[1]);
        a += vp1[2] * tanhf(e1.z + qp1[2]);
        a += vp1[3] * tanhf(e1.w + qp1[3]);
#pragma unroll
        for (int off = 32; off; off >>= 1) a += __shfl_down(a, off);
        if (l == 0) sc[s] = a;
    }
    __syncthreads();

    if (tid < 256) {
        float m = sc[tid];
#pragma unroll
        for (int off = 32; off; off >>= 1) m = fmaxf(m, __shfl_down(m, off));
        if ((tid & 63) == 0) red[tid >> 6] = m;
    }
    __syncthreads();
    if (tid < 256) {
        float mx = fmaxf(fmaxf(red[0], red[1]), fmaxf(red[2], red[3]));
        float e = expf(sc[tid] - mx);
        sc[tid] = e;
        float ssum = e;
#pragma unroll
        for (int off = 32; off; off >>= 1) ssum += __shfl_down(ssum, off);
        if ((tid & 63) == 0) red[8 + (tid >> 6)] = ssum;
    }
    __syncthreads();
    const float inv = 1.0f / (red[8] + red[9] + red[10] + red[11]);

    const int h = tid;
    const float* ep = enc + b * 512 + h;
    float acc = 0.f;
#pragma unroll 4
    for (int s = 0; s < 256; s++) {
        acc += sc[s] * ep[(size_t)s * (256 * 512)];
    }
    ctx[b * 512 + h] = acc * inv;
}

// ---------------------------------------------------------------------------
// k_h: hpre_out += [x | ctx | h_prev] @ [W_ih | W_hh]^T   (k-split atomic)
// A: k<64: x[m,k]; k<576: ctx[m,k-64]; else h_prev = (t0? h0 : tanh(hpre_in+b))
// grid (8 nblk, 8 mblk, 8 kchunk), tile 32m x 64n, BK=8, K-chunk=136.
// Also zeroes qpre (for this step's k_outq atomics) — runs after k_attn read q.
// ---------------------------------------------------------------------------
__global__ __launch_bounds__(256) void k_h(
    const float* __restrict__ xin, const float* __restrict__ ctx,
    const float* __restrict__ hpre_in, const float* __restrict__ h0,
    int t0,
    const float* __restrict__ W_ih, const float* __restrict__ W_hh,
    const float* __restrict__ b_ih, const float* __restrict__ b_hh,
    float* __restrict__ hpre_out, float* __restrict__ qpre)
{
    __shared__ float As[8][34];
    __shared__ float Bs[8][68];
    const int tid = threadIdx.x;
    const int bn = blockIdx.x * 64;
    const int bm = blockIdx.y * 32;
    const int k0 = blockIdx.z * 136;

    // zero qpre: 512 blocks x 256 threads = 131072
    {
        int lin = ((blockIdx.z * 8 + blockIdx.y) * 8 + blockIdx.x) * 256 + tid;
        qpre[lin] = 0.f;
    }

    const int tx = tid & 15;       // n/4
    const int ty = tid >> 4;       // m/2
    // A-stage mapping: k = tid&7, m = tid>>3
    const int sa_k = tid & 7;
    const int sa_m = tid >> 3;
    // B-stage mapping: n = tid>>2, k2 = (tid&3)*2
    const int sb_n = tid >> 2;
    const int sb_k = (tid & 3) * 2;

    float acc[2][4];
#pragma unroll
    for (int i = 0; i < 2; i++)
#pragma unroll
        for (int j = 0; j < 4; j++) acc[i][j] = 0.f;

    for (int kt = 0; kt < 17; kt++) {
        const int kb = k0 + kt * 8;
        // stage A (32m x 8k)
        {
            int m = bm + sa_m;
            int k = kb + sa_k;
            float v;
            if (k < 64) v = xin[m * 64 + k];
            else if (k < 576) v = ctx[m * 512 + (k - 64)];
            else {
                int kh = k - 576;
                v = t0 ? h0[m * 512 + kh]
                       : tanhf(hpre_in[m * 512 + kh] + b_ih[kh] + b_hh[kh]);
            }
            As[sa_k][sa_m] = v;
        }
        // stage B (8k x 64n): B_eff[k][n] = k<576 ? W_ih[n][k] : W_hh[n][k-576]
        {
            int n = bn + sb_n;
#pragma unroll
            for (int i = 0; i < 2; i++) {
                int k = kb + sb_k + i;
                float v = (k < 576) ? W_ih[(size_t)n * 576 + k]
                                    : W_hh[(size_t)n * 512 + (k - 576)];
                Bs[sb_k + i][sb_n] = v;
            }
        }
        __syncthreads();
#pragma unroll
        for (int kk = 0; kk < 8; kk++) {
            float a0 = As[kk][ty * 2], a1 = As[kk][ty * 2 + 1];
            float b0 = Bs[kk][tx * 4], b1 = Bs[kk][tx * 4 + 1];
            float b2 = Bs[kk][tx * 4 + 2], b3 = Bs[kk][tx * 4 + 3];
            acc[0][0] += a0 * b0; acc[0][1] += a0 * b1;
            acc[0][2] += a0 * b2; acc[0][3] += a0 * b3;
            acc[1][0] += a1 * b0; acc[1][1] += a1 * b1;
            acc[1][2] += a1 * b2; acc[1][3] += a1 * b3;
        }
        __syncthreads();
    }
#pragma unroll
    for (int i = 0; i < 2; i++) {
        int m = bm + ty * 2 + i;
#pragma unroll
        for (int j = 0; j < 4; j++) {
            atomicAdd(&hpre_out[(size_t)m * 512 + bn + tx * 4 + j], acc[i][j]);
        }
    }
}

// ---------------------------------------------------------------------------
// k_outq: combined N=576: n<64: ob += h @ Wo^T ; n>=64: qpre += h @ Wa_top
// h[m][k] = tanhf(hpre_cur[m][k] + b_ih[k] + b_hh[k])
// grid (9 nblk, 8 mblk, 4 kchunk), tile 32m x 64n, BK=8, K-chunk=128.
// ---------------------------------------------------------------------------
__global__ __launch_bounds__(256) void k_outq(
    const float* __restrict__ hpre_cur,
    const float* __restrict__ b_ih, const float* __restrict__ b_hh,
    const float* __restrict__ Wo, const float* __restrict__ Wa,
    float* __restrict__ ob, float* __restrict__ qpre)
{
    __shared__ float As[8][34];
    __shared__ float Bs[8][68];
    const int tid = threadIdx.x;
    const int bn = blockIdx.x * 64;        // 0..575
    const int bm = blockIdx.y * 32;
    const int k0 = blockIdx.z * 128;
    const bool is_out = (bn < 64);

    const int tx = tid & 15;
    const int ty = tid >> 4;
    const int sa_k = tid & 7;
    const int sa_m = tid >> 3;
    const int sb_n = tid >> 2;             // for Wo path
    const int sb_k = (tid & 3) * 2;
    const int qa_k = tid >> 5;             // for Wa path: k = tid>>5 (0..7)
    const int qa_n = (tid & 31) * 2;       // 2 consecutive n

    float acc[2][4];
#pragma unroll
    for (int i = 0; i < 2; i++)
#pragma unroll
        for (int j = 0; j < 4; j++) acc[i][j] = 0.f;

    for (int kt = 0; kt < 16; kt++) {
        const int kb = k0 + kt * 8;
        {
            int m = bm + sa_m;
            int k = kb + sa_k;
            As[sa_k][sa_m] = tanhf(hpre_cur[(size_t)m * 512 + k] + b_ih[k] + b_hh[k]);
        }
        if (is_out) {
            int n = bn + sb_n;
#pragma unroll
            for (int i = 0; i < 2; i++) {
                int k = kb + sb_k + i;
                Bs[sb_k + i][sb_n] = Wo[(size_t)n * 512 + k];
            }
        } else {
            int k = kb + qa_k;
            int n = bn - 64 + qa_n;
#pragma unroll
            for (int i = 0; i < 2; i++)
                Bs[qa_k][qa_n + i] = Wa[(size_t)k * 512 + n + i];
        }
        __syncthreads();
#pragma unroll
        for (int kk = 0; kk < 8; kk++) {
            float a0 = As[kk][ty * 2], a1 = As[kk][ty * 2 + 1];
            float b0 = Bs[kk][tx * 4], b1 = Bs[kk][tx * 4 + 1];
            float b2 = Bs[kk][tx * 4 + 2], b3 = Bs[kk][tx * 4 + 3];
            acc[0][0] += a0 * b0; acc[0][1] += a0 * b1;
            acc[0][2] += a0 * b2; acc[0][3] += a0 * b3;
            acc[1][0] += a1 * b0; acc[1][1] += a1 * b1;
            acc[1][2] += a1 * b2; acc[1][3] += a1 * b3;
        }
        __syncthreads();
    }
#pragma unroll
    for (int i = 0; i < 2; i++) {
        int m = bm + ty * 2 + i;
#pragma unroll
        for (int j = 0; j < 4; j++) {
            int n = bn + tx * 4 + j;
            if (is_out) atomicAdd(&ob[m * 64 + n], acc[i][j]);
            else        atomicAdd(&qpre[(size_t)m * 512 + (n - 64)], acc[i][j]);
        }
    }
}

// ---------------------------------------------------------------------------
// k_argmax: out = ob + bo; write dout[b][n][t]; x_next = one_hot(argmax).
// first-index tie-break matches jnp.argmax.
// ---------------------------------------------------------------------------
__global__ __launch_bounds__(256) void k_argmax(const float* __restrict__ ob,
                                                const float* __restrict__ bo,
                                                float* __restrict__ dout, int t,
                                                float* __restrict__ x)
{
    const int b = blockIdx.x * 4 + (threadIdx.x >> 6);
    const int l = threadIdx.x & 63;
    float v = ob[b * 64 + l] + bo[l];
    dout[(size_t)b * (OO * NSTEP) + l * NSTEP + t] = v;
    int bi = l;
    float bv = v;
#pragma unroll
    for (int off = 1; off < 64; off <<= 1) {
        float ov = __shfl_xor(bv, off);
        int oi = __shfl_xor(bi, off);
        if (ov > bv || (ov == bv && oi < bi)) { bv = ov; bi = oi; }
    }
    x[b * 64 + l] = (l == bi) ? 1.0f : 0.0f;
}

// ---------------------------------------------------------------------------
extern "C" void kernel_launch(void* const* d_in, const int* in_sizes, int n_in,
                              void* d_out, int out_size, void* d_ws, size_t ws_size,
                              hipStream_t stream)
{
    const float* sos  = (const float*)d_in[0];
    const float* h0   = (const float*)d_in[1];
    const float* enc  = (const float*)d_in[2];
    const float* Wa   = (const float*)d_in[3];
    const float* ba   = (const float*)d_in[4];
    const float* vvec = (const float*)d_in[5];
    const float* W_ih = (const float*)d_in[6];
    const float* b_ih = (const float*)d_in[7];
    const float* W_hh = (const float*)d_in[8];
    const float* b_hh = (const float*)d_in[9];
    const float* Wo   = (const float*)d_in[10];
    const float* bo   = (const float*)d_in[11];
    float* out = (float*)d_out;

    // Workspace: exactly 34,111,488 floats (136.4 MB) — the known-good budget.
    float* ws = (float*)d_ws;
    float* EW    = ws; ws += (size_t)SS * BB * HH;   // 33,554,432  [b][s][h]
    float* qpre  = ws; ws += BB * HH;                // pre-bias q
    float* ctx   = ws; ws += BB * HH;
    float* hpre0 = ws; ws += BB * HH;                // pre-activation h
    float* hpre1 = ws; ws += BB * HH;
    float* xb    = ws; ws += BB * OO;
    float* ob    = ws; ws += BB * OO;                // pre-bias out

    // ---- Precompute ----
    k_ew_gemm<<<dim3(512, 4), 256, 0, stream>>>(enc, Wa + 512 * 512, EW);
    k_qinit<<<dim3(16, 8), 256, 0, stream>>>(h0, Wa, qpre);

    // ---- 63 decode steps ----
    for (int t = 0; t < NSTEP; t++) {
        float* hpre_out = (t & 1) ? hpre1 : hpre0;
        float* hpre_in  = (t & 1) ? hpre0 : hpre1;   // valid for t>=1
        const float* xin = (t == 0) ? sos : xb;

        // attention (+ zero hpre_out, ob)
        k_attn<<<256, 512, 0, stream>>>(EW, enc, qpre, ba, vvec, ctx,
                                        hpre_out, ob);

        // hpre_out += [x|ctx|h_prev] @ Wcat^T   (+ zero qpre)
        k_h<<<dim3(8, 8, 8), 256, 0, stream>>>(xin, ctx, hpre_in, h0, (t == 0) ? 1 : 0,
                                               W_ih, W_hh, b_ih, b_hh,
                                               hpre_out, qpre);

        // ob += h @ Wo^T ; qpre += h @ Wa_top
        k_outq<<<dim3(9, 8, 4), 256, 0, stream>>>(hpre_out, b_ih, b_hh,
                                                  Wo, Wa, ob, qpre);

        // out store + argmax -> one-hot x
        k_argmax<<<64, 256, 0, stream>>>(ob, bo, out, t, xb);
    }
}